// Round 5
// baseline (648.965 us; speedup 1.0000x reference)
//
#include <hip/hip_runtime.h>
#include <hip/hip_bf16.h>
#include <hip/hip_fp16.h>

#define L_SEQ 16384
#define HDIM  1024
#define CH    32
#define NC    (L_SEQ / CH)   // 512 chunks

typedef _Float16 f16;
typedef _Float16 f16x8 __attribute__((ext_vector_type(8)));
typedef _Float16 f16x4 __attribute__((ext_vector_type(4)));
typedef float    f32x4 __attribute__((ext_vector_type(4)));

#define AS1(p) (const __attribute__((address_space(1))) void*)(p)
#define AS3(p) (__attribute__((address_space(3))) void*)(p)

// -------- weight convert + transpose: out[n*K+k] = (f16) in[k*N+n] --------
__global__ __launch_bounds__(256) void wcvt_t(const float* __restrict__ in,
                                              f16* __restrict__ out, int K, int N) {
  __shared__ float tile[32][33];
  int n0 = blockIdx.x * 32, k0 = blockIdx.y * 32;
  int tx = threadIdx.x, ty = threadIdx.y;  // (32,8)
#pragma unroll
  for (int i = 0; i < 4; i++) {
    int k = k0 + ty + i * 8;
    tile[ty + i * 8][tx] = in[(size_t)k * N + n0 + tx];
  }
  __syncthreads();
#pragma unroll
  for (int i = 0; i < 4; i++) {
    int n = n0 + ty + i * 8;
    out[(size_t)n * K + k0 + tx] = (f16)tile[tx][ty + i * 8];
  }
}

// -------- LayerNorm fp32 in -> f16 out (+ optional f16 copy of input) -----
__global__ __launch_bounds__(256) void ln_k(const float* __restrict__ x,
                                            const float* __restrict__ w,
                                            const float* __restrict__ b,
                                            f16* __restrict__ out,
                                            f16* __restrict__ xcopy) {
  int row = blockIdx.x;
  int t = threadIdx.x;
  const float4* xr = (const float4*)(x + (size_t)row * HDIM);
  float4 v = xr[t];
  float s  = v.x + v.y + v.z + v.w;
  float s2 = v.x * v.x + v.y * v.y + v.z * v.z + v.w * v.w;
#pragma unroll
  for (int off = 32; off > 0; off >>= 1) {
    s  += __shfl_down(s, off);
    s2 += __shfl_down(s2, off);
  }
  __shared__ float red[8];
  int wid = t >> 6, lane = t & 63;
  if (lane == 0) { red[wid] = s; red[4 + wid] = s2; }
  __syncthreads();
  if (t == 0) {
    red[0] = red[0] + red[1] + red[2] + red[3];
    red[4] = red[4] + red[5] + red[6] + red[7];
  }
  __syncthreads();
  float mean = red[0] * (1.0f / HDIM);
  float var  = red[4] * (1.0f / HDIM) - mean * mean;
  float rstd = rsqrtf(var + 1e-5f);
  float4 ww = ((const float4*)w)[t];
  float4 bb = ((const float4*)b)[t];
  f16x4 o;
  o[0] = (f16)((v.x - mean) * rstd * ww.x + bb.x);
  o[1] = (f16)((v.y - mean) * rstd * ww.y + bb.y);
  o[2] = (f16)((v.z - mean) * rstd * ww.z + bb.z);
  o[3] = (f16)((v.w - mean) * rstd * ww.w + bb.w);
  ((f16x4*)(out + (size_t)row * HDIM))[t] = o;
  if (xcopy) {
    f16x4 c;
    c[0] = (f16)v.x; c[1] = (f16)v.y; c[2] = (f16)v.z; c[3] = (f16)v.w;
    ((f16x4*)(xcopy + (size_t)row * HDIM))[t] = c;
  }
}

// -------- LayerNorm f16 in -> f16 out, 128 thr/row, f16x8 loads --------
__global__ __launch_bounds__(128) void ln_k16(const f16* __restrict__ x,
                                              const float* __restrict__ w,
                                              const float* __restrict__ b,
                                              f16* __restrict__ out) {
  int row = blockIdx.x;
  int t = threadIdx.x;  // 0..127
  f16x8 xv = ((const f16x8*)(x + (size_t)row * HDIM))[t];
  float v[8];
  float s = 0.f, s2 = 0.f;
#pragma unroll
  for (int i = 0; i < 8; i++) {
    v[i] = (float)xv[i];
    s += v[i]; s2 += v[i] * v[i];
  }
#pragma unroll
  for (int off = 32; off > 0; off >>= 1) {
    s  += __shfl_down(s, off);
    s2 += __shfl_down(s2, off);
  }
  __shared__ float red[4];
  int wid = t >> 6, lane = t & 63;
  if (lane == 0) { red[wid] = s; red[2 + wid] = s2; }
  __syncthreads();
  float mean = (red[0] + red[1]) * (1.0f / HDIM);
  float var  = (red[2] + red[3]) * (1.0f / HDIM) - mean * mean;
  float rstd = rsqrtf(var + 1e-5f);
  float4 w1 = ((const float4*)w)[2 * t], w2 = ((const float4*)w)[2 * t + 1];
  float4 b1 = ((const float4*)b)[2 * t], b2 = ((const float4*)b)[2 * t + 1];
  float wv[8] = {w1.x, w1.y, w1.z, w1.w, w2.x, w2.y, w2.z, w2.w};
  float bv[8] = {b1.x, b1.y, b1.z, b1.w, b2.x, b2.y, b2.z, b2.w};
  f16x8 o;
#pragma unroll
  for (int i = 0; i < 8; i++) o[i] = (f16)((v[i] - mean) * rstd * wv[i] + bv[i]);
  ((f16x8*)(out + (size_t)row * HDIM))[t] = o;
}

// -------- GEMM: C[M,N] = act(A[M,K] @ BT[N,K]^T + bias) (+f16 resid) --------
// R10: R0's verified 2-phase inner loop upgraded to PREFETCH DISTANCE 2:
// 3-buffer LDS rotation (3x16KB = 48KB -> 3 blocks/CU), tile t's loads
// issued at iter t-2, so the top-of-iter wait is a counted vmcnt(4) (t+1's
// 4 loads stay in flight; vmcnt(0) only in the final iter) instead of the
// __syncthreads vmcnt(0) drain that exposed a full DMA round-trip per iter.
// Sequence per iter: [vmcnt(4): tile t landed] [s_barrier: all waves done
// reading t-1 (data already in regs via compiler lgkm waits)] [stage t+2
// into buf (t+2)%3 = (t-1)%3, just freed] [ds_read t] [16 MFMA].
// Keeps: k-slot XOR swizzle (conflict-0, verified R9), XCD banding,
// fragment mapping + epilogue byte-identical to R0/R9.
// MODE: 0=none 2=silu 3=ug-split.
template <int MODE, int RESID, int OUTF16>
__global__ __launch_bounds__(256, 3) void gemm_bt(const f16* __restrict__ A,
                                                  const f16* __restrict__ BT,
                                                  const float* __restrict__ bias,
                                                  const float* __restrict__ bias2,
                                                  const f16* __restrict__ resid,
                                                  void* __restrict__ Cout,
                                                  void* __restrict__ Cout2,
                                                  int M, int N, int K) {
  __shared__ __align__(16) f16 As[3][128 * 32];
  __shared__ __align__(16) f16 Bs[3][128 * 32];
  const int tid  = threadIdx.x;
  const int lane = tid & 63, wid = tid >> 6;
  const int wm = wid >> 1, wn = wid & 1;
  const int quad = lane >> 4, l16 = lane & 15;

  // XCD-banded swizzle over 128x128 tiles
  const int nbx = N >> 7, nby = M >> 7;
  const int b = blockIdx.x;
  const int xcd = b & 7;
  const int i = b >> 3;
  const int strips = nby >> 3;           // row strips per XCD
  const int rs = i / nbx, cb = i - rs * nbx;
  const long m0 = (long)(xcd * strips + rs) << 7;
  const long n0 = (long)cb << 7;

  // staging coords: row stride 64B (32 f16); 256 thr x 16B = 4KB per round.
  // Pre-swizzled global k-slot (rule #21). (srow>>1)&3 invariant under +64.
  const int srow = wid * 16 + (lane >> 2);   // + 64 per round (it)
  const int qs = (lane & 3) ^ ((srow >> 1) & 3);
  const f16* gA = A  + (m0 + srow) * K + qs * 8;
  const f16* gB = BT + (n0 + srow) * K + qs * 8;
  const int sdst = wid * 1024;               // bytes; + 4096 per round

  f32x4 zero = {0.f, 0.f, 0.f, 0.f};
  f32x4 acc[4][4];
#pragma unroll
  for (int i2 = 0; i2 < 4; i2++)
#pragma unroll
    for (int j = 0; j < 4; j++) acc[i2][j] = zero;

  // prologue: stage tiles 0 and 1 into buffers 0 and 1 (8 loads per wave)
#pragma unroll
  for (int pt = 0; pt < 2; ++pt) {
    const int koff = pt << 5;
#pragma unroll
    for (int it = 0; it < 2; ++it) {
      __builtin_amdgcn_global_load_lds(AS1(gA + (size_t)(it * 64) * K + koff),
                                       AS3((char*)As[pt] + it * 4096 + sdst), 16, 0, 0);
      __builtin_amdgcn_global_load_lds(AS1(gB + (size_t)(it * 64) * K + koff),
                                       AS3((char*)Bs[pt] + it * 4096 + sdst), 16, 0, 0);
    }
  }

  const int niter = K >> 5;   // >= 32 for all our shapes
  int cur = 0;
  for (int ki = 0; ki < niter; ++ki) {
    // T4 counted wait: tile ki's 4 loads (issued at iter ki-2) done;
    // tile ki+1's 4 stay in flight. Full drain only on the last iter.
    if (ki < niter - 1) {
      asm volatile("s_waitcnt vmcnt(4)" ::: "memory");
    } else {
      asm volatile("s_waitcnt vmcnt(0)" ::: "memory");
    }
    __builtin_amdgcn_sched_barrier(0);
    __builtin_amdgcn_s_barrier();   // all waves: ki landed, ki-1 reads done
    __builtin_amdgcn_sched_barrier(0);

    // stage ki+2 into buffer (cur+2)%3 == (ki-1)%3 (freed by the barrier)
    if (ki + 2 < niter) {
      const int nb = (cur >= 1) ? cur - 1 : cur + 2;
      const int koff = (ki + 2) << 5;
#pragma unroll
      for (int it = 0; it < 2; ++it) {
        __builtin_amdgcn_global_load_lds(AS1(gA + (size_t)(it * 64) * K + koff),
                                         AS3((char*)As[nb] + it * 4096 + sdst), 16, 0, 0);
        __builtin_amdgcn_global_load_lds(AS1(gB + (size_t)(it * 64) * K + koff),
                                         AS3((char*)Bs[nb] + it * 4096 + sdst), 16, 0, 0);
      }
    }

    // ds_read current tile (swizzled k-slots, conflict-free) + MFMA
    f16x8 af[4], bfr[4];
#pragma unroll
    for (int mi = 0; mi < 4; ++mi) {
      const int ar = wm * 64 + mi * 16 + l16;
      af[mi] = *(const f16x8*)(As[cur] + ar * 32 + ((quad ^ ((ar >> 1) & 3)) << 3));
    }
#pragma unroll
    for (int ni = 0; ni < 4; ++ni) {
      const int br = wn * 64 + ni * 16 + l16;
      bfr[ni] = *(const f16x8*)(Bs[cur] + br * 32 + ((quad ^ ((br >> 1) & 3)) << 3));
    }
#pragma unroll
    for (int mi = 0; mi < 4; ++mi)
#pragma unroll
      for (int ni = 0; ni < 4; ++ni)
        acc[mi][ni] = __builtin_amdgcn_mfma_f32_16x16x32_f16(af[mi], bfr[ni], acc[mi][ni], 0, 0, 0);

    cur = (cur == 2) ? 0 : cur + 1;
  }

  // epilogue: C/D layout col=lane&15, row=quad*4+reg
#pragma unroll
  for (int mi = 0; mi < 4; ++mi) {
#pragma unroll
    for (int ni = 0; ni < 4; ++ni) {
      const long col = n0 + wn * 64 + ni * 16 + l16;
      float bc;
      if (MODE == 3) bc = (col < HDIM) ? bias[col] : bias2[col - HDIM];
      else           bc = bias[col];
#pragma unroll
      for (int r = 0; r < 4; ++r) {
        const long row = m0 + wm * 64 + mi * 16 + quad * 4 + r;
        float v = acc[mi][ni][r] + bc;
        if (MODE == 2) v = v / (1.f + __expf(-v));
        if (MODE == 3) {
          if (col < HDIM) {
            ((f16*)Cout)[row * HDIM + col] = (f16)v;
          } else {
            float g = 1.f / (1.f + __expf(-v));
            ((f16*)Cout2)[row * HDIM + (col - HDIM)] = (f16)g;
          }
        } else {
          if (RESID) v += (float)resid[row * N + col];
          if (OUTF16) ((f16*)Cout)[row * N + col] = (f16)v;
          else        ((float*)Cout)[row * N + col] = v;
        }
      }
    }
  }
}

// -------- scan pass 1: per-chunk local fwd & bwd carries (one read pass) ----
__global__ __launch_bounds__(256) void scan_p1(const f16* __restrict__ u,
                                               const float* __restrict__ sdecay,
                                               float* __restrict__ carry_f,
                                               float* __restrict__ carry_b) {
  int tid = blockIdx.x * 256 + threadIdx.x;
  int h = tid & (HDIM - 1);
  int c = tid >> 10;
  float d = 1.f / (1.f + expf(-sdecay[h]));
  const f16* up = u + (size_t)c * CH * HDIM + h;
  float sf = 0.f, sb = 0.f, p = 1.f;
#pragma unroll
  for (int i = 0; i < CH; i++) {
    float uu = (float)up[i * HDIM];
    sf = d * sf + uu;   // local fwd final
    sb += p * uu;       // local bwd final = sum d^i * u_i
    p *= d;
  }
  carry_f[(size_t)c * HDIM + h] = sf;
  carry_b[(size_t)c * HDIM + h] = sb;
}

// -------- scan pass 2: chunk-level exclusive scans (fwd dir=0, bwd dir=1) --
__global__ __launch_bounds__(256) void scan_p2(const float* __restrict__ sdecay,
                                               const float* __restrict__ carry_f,
                                               const float* __restrict__ carry_b,
                                               float* __restrict__ cin_f,
                                               float* __restrict__ cin_b) {
  int tid = blockIdx.x * 256 + threadIdx.x;  // 2048 threads
  int h = tid & (HDIM - 1);
  int dir = tid >> 10;
  float d = 1.f / (1.f + expf(-sdecay[h]));
  float dT = powf(d, (float)CH);
  float S = 0.f;
  if (dir == 0) {
#pragma unroll 4
    for (int c = 0; c < NC; c++) {
      cin_f[(size_t)c * HDIM + h] = S;
      S = dT * S + carry_f[(size_t)c * HDIM + h];
    }
  } else {
#pragma unroll 4
    for (int c = NC - 1; c >= 0; c--) {
      cin_b[(size_t)c * HDIM + h] = S;
      S = dT * S + carry_b[(size_t)c * HDIM + h];
    }
  }
}

// -------- scan pass 3: re-scan chunk with carries, fuse gate, f16 out ------
__global__ __launch_bounds__(256) void scan_p3(const f16* __restrict__ u,
                                               const f16* __restrict__ gate,
                                               const float* __restrict__ sdecay,
                                               const float* __restrict__ cin_f,
                                               const float* __restrict__ cin_b,
                                               f16* __restrict__ state_out) {
  int tid = blockIdx.x * 256 + threadIdx.x;
  int h = tid & (HDIM - 1);
  int c = tid >> 10;
  float d = 1.f / (1.f + expf(-sdecay[h]));
  const f16* up = u    + (size_t)c * CH * HDIM + h;
  const f16* gp = gate + (size_t)c * CH * HDIM + h;
  f16* op = state_out  + (size_t)c * CH * HDIM + h;
  float ur[CH], sf[CH];
#pragma unroll
  for (int i = 0; i < CH; i++) ur[i] = (float)up[i * HDIM];
  float s = cin_f[(size_t)c * HDIM + h];
#pragma unroll
  for (int i = 0; i < CH; i++) { s = d * s + ur[i]; sf[i] = s; }
  s = cin_b[(size_t)c * HDIM + h];
#pragma unroll
  for (int i = CH - 1; i >= 0; i--) {
    s = d * s + ur[i];
    float g = (float)gp[i * HDIM];
    op[i * HDIM] = (f16)(0.5f * (sf[i] + s) * g);
  }
}

extern "C" void kernel_launch(void* const* d_in, const int* in_sizes, int n_in,
                              void* d_out, int out_size, void* d_ws, size_t ws_size,
                              hipStream_t stream) {
  const float* x      = (const float*)d_in[0];
  const float* ln1_w  = (const float*)d_in[1];
  const float* ln1_b  = (const float*)d_in[2];
  const float* W_in   = (const float*)d_in[3];
  const float* b_in   = (const float*)d_in[4];
  const float* W_gate = (const float*)d_in[5];
  const float* b_gate = (const float*)d_in[6];
  const float* W_out  = (const float*)d_in[7];
  const float* b_out  = (const float*)d_in[8];
  const float* sdecay = (const float*)d_in[9];
  const float* ln2_w  = (const float*)d_in[10];
  const float* ln2_b  = (const float*)d_in[11];
  const float* W_ff1  = (const float*)d_in[12];
  const float* b_ff1  = (const float*)d_in[13];
  const float* W_ff2  = (const float*)d_in[14];
  const float* b_ff2  = (const float*)d_in[15];
  float* out = (float*)d_out;

  char* ws = (char*)d_ws;
  const size_t MB32 = 33554432, MB64 = 67108864;
  f16* hidden = (f16*)(ws);                 // 32MB; reused as state_out
  f16* xh     = (f16*)(ws + MB32);          // 32MB f16 copy of x
  f16* u      = (f16*)(ws + 2 * MB32);      // 32MB; reused as h2
  f16* gate   = (f16*)(ws + 3 * MB32);      // 32MB
  f16* x2h    = (f16*)(ws + 4 * MB32);      // 32MB f16 x2
  f16* ff     = (f16*)(ws + 5 * MB32);      // 64MB
  char* wbase = ws + 5 * MB32 + MB64;
  f16* wt_ug  = (f16*)(wbase);                       // 4MB (2048x1024)
  f16* wt_out = (f16*)(wbase + 4194304);             // 2MB
  f16* wt_ff1 = (f16*)(wbase + 4194304 + 2097152);   // 4MB
  f16* wt_ff2 = (f16*)(wbase + 2 * 4194304 + 2097152); // 4MB
  char* cbase = wbase + 3 * 4194304 + 2097152;
  float* carry_f = (float*)(cbase);
  float* carry_b = (float*)(cbase + 2097152);
  float* cin_f   = (float*)(cbase + 2 * 2097152);
  float* cin_b   = (float*)(cbase + 3 * 2097152);
  f16* state_out = hidden;  // hidden dead after fused u/gate GEMM
  f16* h2        = u;       // u dead after scan_p3

  dim3 tb(32, 8);
  wcvt_t<<<dim3(32, 32), tb, 0, stream>>>(W_in,   wt_ug,                 1024, 1024);
  wcvt_t<<<dim3(32, 32), tb, 0, stream>>>(W_gate, wt_ug + 1024 * 1024,   1024, 1024);
  wcvt_t<<<dim3(32, 32), tb, 0, stream>>>(W_out,  wt_out,                1024, 1024);
  wcvt_t<<<dim3(64, 32), tb, 0, stream>>>(W_ff1,  wt_ff1,                1024, 2048);
  wcvt_t<<<dim3(32, 64), tb, 0, stream>>>(W_ff2,  wt_ff2,                2048, 1024);

  ln_k<<<L_SEQ, 256, 0, stream>>>(x, ln1_w, ln1_b, hidden, xh);

  // fused u + gate: N=2048, split epilogue  (128x16 = 2048 tiles of 128x128)
  gemm_bt<3, 0, 1><<<2048, 256, 0, stream>>>(hidden, wt_ug, b_in, b_gate, nullptr,
                                             u, gate, L_SEQ, 2048, 1024);

  scan_p1<<<2048, 256, 0, stream>>>(u, sdecay, carry_f, carry_b);
  scan_p2<<<8, 256, 0, stream>>>(sdecay, carry_f, carry_b, cin_f, cin_b);
  scan_p3<<<2048, 256, 0, stream>>>(u, gate, sdecay, cin_f, cin_b, state_out);

  // x2 = x + state_out @ W_out + b_out  (f16 out)  (128x8 = 1024 tiles)
  gemm_bt<0, 1, 1><<<1024, 256, 0, stream>>>(state_out, wt_out, b_out, nullptr, xh,
                                             x2h, nullptr, L_SEQ, 1024, 1024);

  ln_k16<<<L_SEQ, 128, 0, stream>>>(x2h, ln2_w, ln2_b, h2);

  gemm_bt<2, 0, 1><<<2048, 256, 0, stream>>>(h2, wt_ff1, b_ff1, nullptr, nullptr,
                                             ff, nullptr, L_SEQ, 2048, 1024);

  // out = x2 + silu(h2@W_ff1) @ W_ff2 + b_ff2  (fp32 out)  (128x8 = 1024 tiles)
  gemm_bt<0, 1, 0><<<1024, 256, 0, stream>>>(ff, wt_ff2, b_ff2, nullptr, x2h,
                                             out, nullptr, L_SEQ, 1024, 2048);
}

// Round 6
// 619.437 us; speedup vs baseline: 1.0477x; 1.0477x over previous
//
#include <hip/hip_runtime.h>
#include <hip/hip_bf16.h>
#include <hip/hip_fp16.h>

#define L_SEQ 16384
#define HDIM  1024
#define CH    32
#define NC    (L_SEQ / CH)   // 512 chunks

typedef _Float16 f16;
typedef _Float16 f16x8 __attribute__((ext_vector_type(8)));
typedef _Float16 f16x4 __attribute__((ext_vector_type(4)));
typedef float    f32x4 __attribute__((ext_vector_type(4)));

#define AS1(p) (const __attribute__((address_space(1))) void*)(p)
#define AS3(p) (__attribute__((address_space(3))) void*)(p)

// -------- weight convert + transpose: out[n*K+k] = (f16) in[k*N+n] --------
__global__ __launch_bounds__(256) void wcvt_t(const float* __restrict__ in,
                                              f16* __restrict__ out, int K, int N) {
  __shared__ float tile[32][33];
  int n0 = blockIdx.x * 32, k0 = blockIdx.y * 32;
  int tx = threadIdx.x, ty = threadIdx.y;  // (32,8)
#pragma unroll
  for (int i = 0; i < 4; i++) {
    int k = k0 + ty + i * 8;
    tile[ty + i * 8][tx] = in[(size_t)k * N + n0 + tx];
  }
  __syncthreads();
#pragma unroll
  for (int i = 0; i < 4; i++) {
    int n = n0 + ty + i * 8;
    out[(size_t)n * K + k0 + tx] = (f16)tile[tx][ty + i * 8];
  }
}

// -------- LayerNorm fp32 in -> f16 out (+ optional f16 copy of input) -----
__global__ __launch_bounds__(256) void ln_k(const float* __restrict__ x,
                                            const float* __restrict__ w,
                                            const float* __restrict__ b,
                                            f16* __restrict__ out,
                                            f16* __restrict__ xcopy) {
  int row = blockIdx.x;
  int t = threadIdx.x;
  const float4* xr = (const float4*)(x + (size_t)row * HDIM);
  float4 v = xr[t];
  float s  = v.x + v.y + v.z + v.w;
  float s2 = v.x * v.x + v.y * v.y + v.z * v.z + v.w * v.w;
#pragma unroll
  for (int off = 32; off > 0; off >>= 1) {
    s  += __shfl_down(s, off);
    s2 += __shfl_down(s2, off);
  }
  __shared__ float red[8];
  int wid = t >> 6, lane = t & 63;
  if (lane == 0) { red[wid] = s; red[4 + wid] = s2; }
  __syncthreads();
  if (t == 0) {
    red[0] = red[0] + red[1] + red[2] + red[3];
    red[4] = red[4] + red[5] + red[6] + red[7];
  }
  __syncthreads();
  float mean = red[0] * (1.0f / HDIM);
  float var  = red[4] * (1.0f / HDIM) - mean * mean;
  float rstd = rsqrtf(var + 1e-5f);
  float4 ww = ((const float4*)w)[t];
  float4 bb = ((const float4*)b)[t];
  f16x4 o;
  o[0] = (f16)((v.x - mean) * rstd * ww.x + bb.x);
  o[1] = (f16)((v.y - mean) * rstd * ww.y + bb.y);
  o[2] = (f16)((v.z - mean) * rstd * ww.z + bb.z);
  o[3] = (f16)((v.w - mean) * rstd * ww.w + bb.w);
  ((f16x4*)(out + (size_t)row * HDIM))[t] = o;
  if (xcopy) {
    f16x4 c;
    c[0] = (f16)v.x; c[1] = (f16)v.y; c[2] = (f16)v.z; c[3] = (f16)v.w;
    ((f16x4*)(xcopy + (size_t)row * HDIM))[t] = c;
  }
}

// -------- LayerNorm f16 in -> f16 out, 128 thr/row, f16x8 loads --------
__global__ __launch_bounds__(128) void ln_k16(const f16* __restrict__ x,
                                              const float* __restrict__ w,
                                              const float* __restrict__ b,
                                              f16* __restrict__ out) {
  int row = blockIdx.x;
  int t = threadIdx.x;  // 0..127
  f16x8 xv = ((const f16x8*)(x + (size_t)row * HDIM))[t];
  float v[8];
  float s = 0.f, s2 = 0.f;
#pragma unroll
  for (int i = 0; i < 8; i++) {
    v[i] = (float)xv[i];
    s += v[i]; s2 += v[i] * v[i];
  }
#pragma unroll
  for (int off = 32; off > 0; off >>= 1) {
    s  += __shfl_down(s, off);
    s2 += __shfl_down(s2, off);
  }
  __shared__ float red[4];
  int wid = t >> 6, lane = t & 63;
  if (lane == 0) { red[wid] = s; red[2 + wid] = s2; }
  __syncthreads();
  float mean = (red[0] + red[1]) * (1.0f / HDIM);
  float var  = (red[2] + red[3]) * (1.0f / HDIM) - mean * mean;
  float rstd = rsqrtf(var + 1e-5f);
  float4 w1 = ((const float4*)w)[2 * t], w2 = ((const float4*)w)[2 * t + 1];
  float4 b1 = ((const float4*)b)[2 * t], b2 = ((const float4*)b)[2 * t + 1];
  float wv[8] = {w1.x, w1.y, w1.z, w1.w, w2.x, w2.y, w2.z, w2.w};
  float bv[8] = {b1.x, b1.y, b1.z, b1.w, b2.x, b2.y, b2.z, b2.w};
  f16x8 o;
#pragma unroll
  for (int i = 0; i < 8; i++) o[i] = (f16)((v[i] - mean) * rstd * wv[i] + bv[i]);
  ((f16x8*)(out + (size_t)row * HDIM))[t] = o;
}

// -------- GEMM: C[M,N] = act(A[M,K] @ BT[N,K]^T + bias) (+f16 resid) --------
// R11 = EXACT R0 verified inner loop (128x128 block, 4 waves 64x64, 2-buffer
// LDS, one __syncthreads per k-iter, 4 blocks/CU, no swizzle) with ONE
// change: SWAPPED MFMA OPERANDS -> transposed C/D fragment mapping.
//   mfma(bfr, af): within-tile l16 -> M-row, quad*4+reg -> N-col.
//   A lane's 4 acc regs are now 4 CONSECUTIVE COLUMNS of one row, so the
//   epilogue packs them into one f16x4 (8B) / float4 (16B) store instead of
//   4 row-strided scalar stores. Stores/thread 64->16; resid loads 64->16;
//   bias becomes a float4 load. Inner loop untouched.
// MODE: 0=none 2=silu 3=ug-split. XCD-banded 1-D grid swizzle.
template <int MODE, int RESID, int OUTF16>
__global__ __launch_bounds__(256, 4) void gemm_bt(const f16* __restrict__ A,
                                                  const f16* __restrict__ BT,
                                                  const float* __restrict__ bias,
                                                  const float* __restrict__ bias2,
                                                  const f16* __restrict__ resid,
                                                  void* __restrict__ Cout,
                                                  void* __restrict__ Cout2,
                                                  int M, int N, int K) {
  __shared__ __align__(16) f16 As[2][128 * 32];
  __shared__ __align__(16) f16 Bs[2][128 * 32];
  const int tid  = threadIdx.x;
  const int lane = tid & 63, wid = tid >> 6;
  const int wm = wid >> 1, wn = wid & 1;
  const int quad = lane >> 4, l16 = lane & 15;

  // XCD-banded swizzle over 128x128 tiles
  const int nbx = N >> 7, nby = M >> 7;
  const int b = blockIdx.x;
  const int xcd = b & 7;
  const int i = b >> 3;
  const int strips = nby >> 3;           // row strips per XCD
  const int rs = i / nbx, cb = i - rs * nbx;
  const long m0 = (long)(xcd * strips + rs) << 7;
  const long n0 = (long)cb << 7;

  // staging coords: row stride 64B (32 f16); 256 thr x 16B = 4KB per round
  const int srow = wid * 16 + (lane >> 2);   // + 64 per round (it)
  const int scol = (lane & 3) * 8;
  const f16* gA = A  + (m0 + srow) * K + scol;
  const f16* gB = BT + (n0 + srow) * K + scol;
  const int sdst = wid * 1024;               // + 4096 per round (wave-uniform)

  f32x4 zero = {0.f, 0.f, 0.f, 0.f};
  f32x4 acc[4][4];
#pragma unroll
  for (int i2 = 0; i2 < 4; i2++)
#pragma unroll
    for (int j = 0; j < 4; j++) acc[i2][j] = zero;

  // prologue: stage k0=0 into buffer 0
#pragma unroll
  for (int it = 0; it < 2; ++it) {
    __builtin_amdgcn_global_load_lds(AS1(gA + (size_t)(it * 64) * K),
                                     AS3((char*)As[0] + it * 4096 + sdst), 16, 0, 0);
    __builtin_amdgcn_global_load_lds(AS1(gB + (size_t)(it * 64) * K),
                                     AS3((char*)Bs[0] + it * 4096 + sdst), 16, 0, 0);
  }
  __syncthreads();

  const int niter = K >> 5;
  for (int ki = 0; ki < niter; ++ki) {
    const int cur = ki & 1;
    // prefetch k+1 into the other buffer (safe: barrier at end of prev iter
    // guaranteed all waves finished reading it)
    if (ki + 1 < niter) {
      const int nxt = cur ^ 1;
      const int koff = (ki + 1) << 5;
#pragma unroll
      for (int it = 0; it < 2; ++it) {
        __builtin_amdgcn_global_load_lds(AS1(gA + (size_t)(it * 64) * K + koff),
                                         AS3((char*)As[nxt] + it * 4096 + sdst), 16, 0, 0);
        __builtin_amdgcn_global_load_lds(AS1(gB + (size_t)(it * 64) * K + koff),
                                         AS3((char*)Bs[nxt] + it * 4096 + sdst), 16, 0, 0);
      }
    }
    f16x8 af[4], bfr[4];
#pragma unroll
    for (int mi = 0; mi < 4; ++mi)
      af[mi] = *(const f16x8*)(As[cur] + (wm * 64 + mi * 16 + l16) * 32 + quad * 8);
#pragma unroll
    for (int ni = 0; ni < 4; ++ni)
      bfr[ni] = *(const f16x8*)(Bs[cur] + (wn * 64 + ni * 16 + l16) * 32 + quad * 8);
    // SWAPPED operand order: D^T mapping (l16 -> M, quad*4+reg -> N)
#pragma unroll
    for (int mi = 0; mi < 4; ++mi)
#pragma unroll
      for (int ni = 0; ni < 4; ++ni)
        acc[mi][ni] = __builtin_amdgcn_mfma_f32_16x16x32_f16(bfr[ni], af[mi], acc[mi][ni], 0, 0, 0);
    // one barrier per iter: drains prefetch DMA (overlapped by compute above)
    // and protects cur buffer from being overwritten next iter
    __syncthreads();
  }

  // epilogue (transposed mapping): row = m0+wm*64+mi*16+l16 (per-thread fixed
  // within mi), cols = n0+wn*64+ni*16+quad*4 .. +3  -> vector stores.
#pragma unroll
  for (int mi = 0; mi < 4; ++mi) {
    const long row = m0 + wm * 64 + mi * 16 + l16;
#pragma unroll
    for (int ni = 0; ni < 4; ++ni) {
      const long col = n0 + wn * 64 + ni * 16 + quad * 4;   // %4 == 0
      const float* bp;
      if (MODE == 3) bp = (col < HDIM) ? (bias + col) : (bias2 + (col - HDIM));
      else           bp = bias + col;
      f32x4 v = acc[mi][ni] + *(const f32x4*)bp;
      if (MODE == 2) {
#pragma unroll
        for (int r = 0; r < 4; ++r) v[r] = v[r] / (1.f + __expf(-v[r]));
      }
      if (MODE == 3) {
        if (col < HDIM) {
          f16x4 o;
#pragma unroll
          for (int r = 0; r < 4; ++r) o[r] = (f16)v[r];
          *(f16x4*)((f16*)Cout + row * HDIM + col) = o;
        } else {
          f16x4 o;
#pragma unroll
          for (int r = 0; r < 4; ++r) o[r] = (f16)(1.f / (1.f + __expf(-v[r])));
          *(f16x4*)((f16*)Cout2 + row * HDIM + (col - HDIM)) = o;
        }
      } else {
        if (RESID) {
          f16x4 rv = *(const f16x4*)(resid + row * N + col);
#pragma unroll
          for (int r = 0; r < 4; ++r) v[r] += (float)rv[r];
        }
        if (OUTF16) {
          f16x4 o;
#pragma unroll
          for (int r = 0; r < 4; ++r) o[r] = (f16)v[r];
          *(f16x4*)((f16*)Cout + row * N + col) = o;
        } else {
          *(f32x4*)((float*)Cout + row * N + col) = v;
        }
      }
    }
  }
}

// -------- scan pass 1: per-chunk local fwd & bwd carries (one read pass) ----
__global__ __launch_bounds__(256) void scan_p1(const f16* __restrict__ u,
                                               const float* __restrict__ sdecay,
                                               float* __restrict__ carry_f,
                                               float* __restrict__ carry_b) {
  int tid = blockIdx.x * 256 + threadIdx.x;
  int h = tid & (HDIM - 1);
  int c = tid >> 10;
  float d = 1.f / (1.f + expf(-sdecay[h]));
  const f16* up = u + (size_t)c * CH * HDIM + h;
  float sf = 0.f, sb = 0.f, p = 1.f;
#pragma unroll
  for (int i = 0; i < CH; i++) {
    float uu = (float)up[i * HDIM];
    sf = d * sf + uu;   // local fwd final
    sb += p * uu;       // local bwd final = sum d^i * u_i
    p *= d;
  }
  carry_f[(size_t)c * HDIM + h] = sf;
  carry_b[(size_t)c * HDIM + h] = sb;
}

// -------- scan pass 2: chunk-level exclusive scans (fwd dir=0, bwd dir=1) --
__global__ __launch_bounds__(256) void scan_p2(const float* __restrict__ sdecay,
                                               const float* __restrict__ carry_f,
                                               const float* __restrict__ carry_b,
                                               float* __restrict__ cin_f,
                                               float* __restrict__ cin_b) {
  int tid = blockIdx.x * 256 + threadIdx.x;  // 2048 threads
  int h = tid & (HDIM - 1);
  int dir = tid >> 10;
  float d = 1.f / (1.f + expf(-sdecay[h]));
  float dT = powf(d, (float)CH);
  float S = 0.f;
  if (dir == 0) {
#pragma unroll 4
    for (int c = 0; c < NC; c++) {
      cin_f[(size_t)c * HDIM + h] = S;
      S = dT * S + carry_f[(size_t)c * HDIM + h];
    }
  } else {
#pragma unroll 4
    for (int c = NC - 1; c >= 0; c--) {
      cin_b[(size_t)c * HDIM + h] = S;
      S = dT * S + carry_b[(size_t)c * HDIM + h];
    }
  }
}

// -------- scan pass 3: re-scan chunk with carries, fuse gate, f16 out ------
__global__ __launch_bounds__(256) void scan_p3(const f16* __restrict__ u,
                                               const f16* __restrict__ gate,
                                               const float* __restrict__ sdecay,
                                               const float* __restrict__ cin_f,
                                               const float* __restrict__ cin_b,
                                               f16* __restrict__ state_out) {
  int tid = blockIdx.x * 256 + threadIdx.x;
  int h = tid & (HDIM - 1);
  int c = tid >> 10;
  float d = 1.f / (1.f + expf(-sdecay[h]));
  const f16* up = u    + (size_t)c * CH * HDIM + h;
  const f16* gp = gate + (size_t)c * CH * HDIM + h;
  f16* op = state_out  + (size_t)c * CH * HDIM + h;
  float ur[CH], sf[CH];
#pragma unroll
  for (int i = 0; i < CH; i++) ur[i] = (float)up[i * HDIM];
  float s = cin_f[(size_t)c * HDIM + h];
#pragma unroll
  for (int i = 0; i < CH; i++) { s = d * s + ur[i]; sf[i] = s; }
  s = cin_b[(size_t)c * HDIM + h];
#pragma unroll
  for (int i = CH - 1; i >= 0; i--) {
    s = d * s + ur[i];
    float g = (float)gp[i * HDIM];
    op[i * HDIM] = (f16)(0.5f * (sf[i] + s) * g);
  }
}

extern "C" void kernel_launch(void* const* d_in, const int* in_sizes, int n_in,
                              void* d_out, int out_size, void* d_ws, size_t ws_size,
                              hipStream_t stream) {
  const float* x      = (const float*)d_in[0];
  const float* ln1_w  = (const float*)d_in[1];
  const float* ln1_b  = (const float*)d_in[2];
  const float* W_in   = (const float*)d_in[3];
  const float* b_in   = (const float*)d_in[4];
  const float* W_gate = (const float*)d_in[5];
  const float* b_gate = (const float*)d_in[6];
  const float* W_out  = (const float*)d_in[7];
  const float* b_out  = (const float*)d_in[8];
  const float* sdecay = (const float*)d_in[9];
  const float* ln2_w  = (const float*)d_in[10];
  const float* ln2_b  = (const float*)d_in[11];
  const float* W_ff1  = (const float*)d_in[12];
  const float* b_ff1  = (const float*)d_in[13];
  const float* W_ff2  = (const float*)d_in[14];
  const float* b_ff2  = (const float*)d_in[15];
  float* out = (float*)d_out;

  char* ws = (char*)d_ws;
  const size_t MB32 = 33554432, MB64 = 67108864;
  f16* hidden = (f16*)(ws);                 // 32MB; reused as state_out
  f16* xh     = (f16*)(ws + MB32);          // 32MB f16 copy of x
  f16* u      = (f16*)(ws + 2 * MB32);      // 32MB; reused as h2
  f16* gate   = (f16*)(ws + 3 * MB32);      // 32MB
  f16* x2h    = (f16*)(ws + 4 * MB32);      // 32MB f16 x2
  f16* ff     = (f16*)(ws + 5 * MB32);      // 64MB
  char* wbase = ws + 5 * MB32 + MB64;
  f16* wt_ug  = (f16*)(wbase);                       // 4MB (2048x1024)
  f16* wt_out = (f16*)(wbase + 4194304);             // 2MB
  f16* wt_ff1 = (f16*)(wbase + 4194304 + 2097152);   // 4MB
  f16* wt_ff2 = (f16*)(wbase + 2 * 4194304 + 2097152); // 4MB
  char* cbase = wbase + 3 * 4194304 + 2097152;
  float* carry_f = (float*)(cbase);
  float* carry_b = (float*)(cbase + 2097152);
  float* cin_f   = (float*)(cbase + 2 * 2097152);
  float* cin_b   = (float*)(cbase + 3 * 2097152);
  f16* state_out = hidden;  // hidden dead after fused u/gate GEMM
  f16* h2        = u;       // u dead after scan_p3

  dim3 tb(32, 8);
  wcvt_t<<<dim3(32, 32), tb, 0, stream>>>(W_in,   wt_ug,                 1024, 1024);
  wcvt_t<<<dim3(32, 32), tb, 0, stream>>>(W_gate, wt_ug + 1024 * 1024,   1024, 1024);
  wcvt_t<<<dim3(32, 32), tb, 0, stream>>>(W_out,  wt_out,                1024, 1024);
  wcvt_t<<<dim3(64, 32), tb, 0, stream>>>(W_ff1,  wt_ff1,                1024, 2048);
  wcvt_t<<<dim3(32, 64), tb, 0, stream>>>(W_ff2,  wt_ff2,                2048, 1024);

  ln_k<<<L_SEQ, 256, 0, stream>>>(x, ln1_w, ln1_b, hidden, xh);

  // fused u + gate: N=2048, split epilogue  (128x16 = 2048 tiles of 128x128)
  gemm_bt<3, 0, 1><<<2048, 256, 0, stream>>>(hidden, wt_ug, b_in, b_gate, nullptr,
                                             u, gate, L_SEQ, 2048, 1024);

  scan_p1<<<2048, 256, 0, stream>>>(u, sdecay, carry_f, carry_b);
  scan_p2<<<8, 256, 0, stream>>>(sdecay, carry_f, carry_b, cin_f, cin_b);
  scan_p3<<<2048, 256, 0, stream>>>(u, gate, sdecay, cin_f, cin_b, state_out);

  // x2 = x + state_out @ W_out + b_out  (f16 out)  (128x8 = 1024 tiles)
  gemm_bt<0, 1, 1><<<1024, 256, 0, stream>>>(state_out, wt_out, b_out, nullptr, xh,
                                             x2h, nullptr, L_SEQ, 1024, 1024);

  ln_k16<<<L_SEQ, 128, 0, stream>>>(x2h, ln2_w, ln2_b, h2);

  gemm_bt<2, 0, 1><<<2048, 256, 0, stream>>>(h2, wt_ff1, b_ff1, nullptr, nullptr,
                                             ff, nullptr, L_SEQ, 2048, 1024);

  // out = x2 + silu(h2@W_ff1) @ W_ff2 + b_ff2  (fp32 out)  (128x8 = 1024 tiles)
  gemm_bt<0, 1, 0><<<1024, 256, 0, stream>>>(ff, wt_ff2, b_ff2, nullptr, x2h,
                                             out, nullptr, L_SEQ, 1024, 2048);
}

// Round 7
// 592.803 us; speedup vs baseline: 1.0947x; 1.0449x over previous
//
#include <hip/hip_runtime.h>
#include <hip/hip_bf16.h>
#include <hip/hip_fp16.h>

#define L_SEQ 16384
#define HDIM  1024
#define CH    32
#define NC    (L_SEQ / CH)   // 512 chunks

typedef _Float16 f16;
typedef _Float16 f16x8 __attribute__((ext_vector_type(8)));
typedef _Float16 f16x4 __attribute__((ext_vector_type(4)));
typedef float    f32x4 __attribute__((ext_vector_type(4)));

#define AS1(p) (const __attribute__((address_space(1))) void*)(p)
#define AS3(p) (__attribute__((address_space(3))) void*)(p)

// -------- weight convert + transpose: out[n*K+k] = (f16) in[k*N+n] --------
__global__ __launch_bounds__(256) void wcvt_t(const float* __restrict__ in,
                                              f16* __restrict__ out, int K, int N) {
  __shared__ float tile[32][33];
  int n0 = blockIdx.x * 32, k0 = blockIdx.y * 32;
  int tx = threadIdx.x, ty = threadIdx.y;  // (32,8)
#pragma unroll
  for (int i = 0; i < 4; i++) {
    int k = k0 + ty + i * 8;
    tile[ty + i * 8][tx] = in[(size_t)k * N + n0 + tx];
  }
  __syncthreads();
#pragma unroll
  for (int i = 0; i < 4; i++) {
    int n = n0 + ty + i * 8;
    out[(size_t)n * K + k0 + tx] = (f16)tile[tx][ty + i * 8];
  }
}

// -------- LayerNorm fp32 in -> f16 out (+ optional f16 copy of input) -----
__global__ __launch_bounds__(256) void ln_k(const float* __restrict__ x,
                                            const float* __restrict__ w,
                                            const float* __restrict__ b,
                                            f16* __restrict__ out,
                                            f16* __restrict__ xcopy) {
  int row = blockIdx.x;
  int t = threadIdx.x;
  const float4* xr = (const float4*)(x + (size_t)row * HDIM);
  float4 v = xr[t];
  float s  = v.x + v.y + v.z + v.w;
  float s2 = v.x * v.x + v.y * v.y + v.z * v.z + v.w * v.w;
#pragma unroll
  for (int off = 32; off > 0; off >>= 1) {
    s  += __shfl_down(s, off);
    s2 += __shfl_down(s2, off);
  }
  __shared__ float red[8];
  int wid = t >> 6, lane = t & 63;
  if (lane == 0) { red[wid] = s; red[4 + wid] = s2; }
  __syncthreads();
  if (t == 0) {
    red[0] = red[0] + red[1] + red[2] + red[3];
    red[4] = red[4] + red[5] + red[6] + red[7];
  }
  __syncthreads();
  float mean = red[0] * (1.0f / HDIM);
  float var  = red[4] * (1.0f / HDIM) - mean * mean;
  float rstd = rsqrtf(var + 1e-5f);
  float4 ww = ((const float4*)w)[t];
  float4 bb = ((const float4*)b)[t];
  f16x4 o;
  o[0] = (f16)((v.x - mean) * rstd * ww.x + bb.x);
  o[1] = (f16)((v.y - mean) * rstd * ww.y + bb.y);
  o[2] = (f16)((v.z - mean) * rstd * ww.z + bb.z);
  o[3] = (f16)((v.w - mean) * rstd * ww.w + bb.w);
  ((f16x4*)(out + (size_t)row * HDIM))[t] = o;
  if (xcopy) {
    f16x4 c;
    c[0] = (f16)v.x; c[1] = (f16)v.y; c[2] = (f16)v.z; c[3] = (f16)v.w;
    ((f16x4*)(xcopy + (size_t)row * HDIM))[t] = c;
  }
}

// -------- LayerNorm f16 in -> f16 out, 128 thr/row, f16x8 loads --------
__global__ __launch_bounds__(128) void ln_k16(const f16* __restrict__ x,
                                              const float* __restrict__ w,
                                              const float* __restrict__ b,
                                              f16* __restrict__ out) {
  int row = blockIdx.x;
  int t = threadIdx.x;  // 0..127
  f16x8 xv = ((const f16x8*)(x + (size_t)row * HDIM))[t];
  float v[8];
  float s = 0.f, s2 = 0.f;
#pragma unroll
  for (int i = 0; i < 8; i++) {
    v[i] = (float)xv[i];
    s += v[i]; s2 += v[i] * v[i];
  }
#pragma unroll
  for (int off = 32; off > 0; off >>= 1) {
    s  += __shfl_down(s, off);
    s2 += __shfl_down(s2, off);
  }
  __shared__ float red[4];
  int wid = t >> 6, lane = t & 63;
  if (lane == 0) { red[wid] = s; red[2 + wid] = s2; }
  __syncthreads();
  float mean = (red[0] + red[1]) * (1.0f / HDIM);
  float var  = (red[2] + red[3]) * (1.0f / HDIM) - mean * mean;
  float rstd = rsqrtf(var + 1e-5f);
  float4 w1 = ((const float4*)w)[2 * t], w2 = ((const float4*)w)[2 * t + 1];
  float4 b1 = ((const float4*)b)[2 * t], b2 = ((const float4*)b)[2 * t + 1];
  float wv[8] = {w1.x, w1.y, w1.z, w1.w, w2.x, w2.y, w2.z, w2.w};
  float bv[8] = {b1.x, b1.y, b1.z, b1.w, b2.x, b2.y, b2.z, b2.w};
  f16x8 o;
#pragma unroll
  for (int i = 0; i < 8; i++) o[i] = (f16)((v[i] - mean) * rstd * wv[i] + bv[i]);
  ((f16x8*)(out + (size_t)row * HDIM))[t] = o;
}

// -------- GEMM: C[M,N] = act(A[M,K] @ BT[N,K]^T + bias) (+f16 resid) --------
// R12: 256x256 tile, BK=32, 8 waves (2Mx4N -> 128x64 per wave), STATIC 64KB
// LDS (2buf x 256x32 x A,B), 2 interleaved phases per K-tile:
//   phase = { ds_read frags ; issue 2 stage-DMAs (tile t+1) ; s_barrier ;
//             lgkmcnt(0) ; setprio(1) ; 16 MFMA ; setprio(0) }
// Stage loads drain only at the NEXT iter top (vmcnt(0)+barrier, distance =
// one full K-tile of compute) — no mid-iter drain (T3/T4 mechanism, m196/
// m248: 256^2 8ph at K=1024 = +10..29% over 2ph). Built to dodge the three
// measured failure causes: 64KB not 128KB (R10), per-phase interleave not
// coarse lockstep (R6), no VGPR squeeze (R9).
// + T2 swizzle, involution q^((row>>1)&3) (verified R9: conflict 8.4M -> 0):
//   linear DMA dest, pre-swizzled global source, same XOR on ds_read.
// + R11's verified swapped-operand vector epilogue (f16x4/f32x4 stores).
// Race ledger: RAW buf[cur] <- vmcnt(0)+barrier at iter top (per-wave vmcnt
// made global by the barrier); WAR buf[nxt] <- same barrier (all prior
// ds_reads retired at their lgkmcnt(0) before the owning wave's MFMA).
// MODE: 0=none 2=silu 3=ug-split. XCD-banded 1-D grid swizzle.
template <int MODE, int RESID, int OUTF16>
__global__ __launch_bounds__(512, 2) void gemm256(const f16* __restrict__ A,
                                                  const f16* __restrict__ BT,
                                                  const float* __restrict__ bias,
                                                  const float* __restrict__ bias2,
                                                  const f16* __restrict__ resid,
                                                  void* __restrict__ Cout,
                                                  void* __restrict__ Cout2,
                                                  int M, int N, int K) {
  __shared__ __align__(16) f16 As[2][256 * 32];   // 2 x 16KB
  __shared__ __align__(16) f16 Bs[2][256 * 32];   // 2 x 16KB
  const int tid  = threadIdx.x;
  const int lane = tid & 63;
  const int wid  = tid >> 6;                 // 8 waves
  const int wm = wid >> 2, wn = wid & 3;     // 2 x 4 wave grid
  const int quad = lane >> 4, l16 = lane & 15;
  const int xq = (quad ^ ((l16 >> 1) & 3)) << 4;   // swizzled 16B slot (bytes)

  // XCD-banded swizzle over 256x256 tiles
  const int nbx = N >> 8, nby = M >> 8;
  const int b = blockIdx.x;
  const int xcd = b & 7;
  const int i = b >> 3;
  const int strips = nby >> 3;               // row strips per XCD
  const int rs = i / nbx, cb = i - rs * nbx;
  const long m0 = (long)(xcd * strips + rs) << 8;
  const long n0 = (long)cb << 8;

  // staging: unit = 128 rows x 32 k = 8KB = 512 thr x 16B (1 load each).
  // dest row = tid>>2, phys slot = tid&3; logical source slot pre-swizzled:
  // qs = (tid&3) ^ ((row>>1)&3) = (tid&3) ^ ((tid>>3)&3)   (rule #21)
  const int srow = tid >> 2;
  const int qs = (tid & 3) ^ ((tid >> 3) & 3);
  const f16* gA = A  + (size_t)(m0 + srow) * K + qs * 8;
  const f16* gB = BT + (size_t)(n0 + srow) * K + qs * 8;
  const int sdst = tid * 16;                 // byte offset within an 8KB unit

  f32x4 zero = {0.f, 0.f, 0.f, 0.f};
  f32x4 acc[8][4];
#pragma unroll
  for (int mi = 0; mi < 8; ++mi)
#pragma unroll
    for (int ni = 0; ni < 4; ++ni) acc[mi][ni] = zero;

  // prologue: stage tile 0 (A h0,h1 + B h0,h1) into buffer 0
#pragma unroll
  for (int h = 0; h < 2; ++h) {
    __builtin_amdgcn_global_load_lds(AS1(gA + (size_t)h * 128 * K),
                                     AS3((char*)As[0] + h * 8192 + sdst), 16, 0, 0);
    __builtin_amdgcn_global_load_lds(AS1(gB + (size_t)h * 128 * K),
                                     AS3((char*)Bs[0] + h * 8192 + sdst), 16, 0, 0);
  }

  const int nt = K >> 5;
  int cur = 0;
  for (int t = 0; t < nt; ++t) {
    // tile t's loads (issued last iter / prologue) landed, for ALL waves
    asm volatile("s_waitcnt vmcnt(0)" ::: "memory");
    __builtin_amdgcn_sched_barrier(0);
    __builtin_amdgcn_s_barrier();
    const f16* Ab = As[cur];
    const f16* Bb = Bs[cur];
    const int nxt = cur ^ 1;

    // ---- phase 0: A-frags mi 0-3 + all B-frags; stage A of t+1 ----
    f16x8 af[4], bf[4];
#pragma unroll
    for (int mi = 0; mi < 4; ++mi) {
      const int row = wm * 128 + mi * 16 + l16;
      af[mi] = *(const f16x8*)((const char*)Ab + row * 64 + xq);
    }
#pragma unroll
    for (int ni = 0; ni < 4; ++ni) {
      const int row = wn * 64 + ni * 16 + l16;
      bf[ni] = *(const f16x8*)((const char*)Bb + row * 64 + xq);
    }
    if (t + 1 < nt) {
      const size_t koff = (size_t)(t + 1) * 32;
#pragma unroll
      for (int h = 0; h < 2; ++h)
        __builtin_amdgcn_global_load_lds(AS1(gA + (size_t)h * 128 * K + koff),
                                         AS3((char*)As[nxt] + h * 8192 + sdst), 16, 0, 0);
    }
    __builtin_amdgcn_s_barrier();
    asm volatile("s_waitcnt lgkmcnt(0)" ::: "memory");
    __builtin_amdgcn_sched_barrier(0);
    __builtin_amdgcn_s_setprio(1);
#pragma unroll
    for (int mi = 0; mi < 4; ++mi)
#pragma unroll
      for (int ni = 0; ni < 4; ++ni)
        acc[mi][ni] = __builtin_amdgcn_mfma_f32_16x16x32_f16(bf[ni], af[mi], acc[mi][ni], 0, 0, 0);
    __builtin_amdgcn_s_setprio(0);
    __builtin_amdgcn_sched_barrier(0);
    __builtin_amdgcn_s_barrier();

    // ---- phase 1: A-frags mi 4-7 (B held in regs); stage B of t+1 ----
    f16x8 af2[4];
#pragma unroll
    for (int mi = 0; mi < 4; ++mi) {
      const int row = wm * 128 + (4 + mi) * 16 + l16;
      af2[mi] = *(const f16x8*)((const char*)Ab + row * 64 + xq);
    }
    if (t + 1 < nt) {
      const size_t koff = (size_t)(t + 1) * 32;
#pragma unroll
      for (int h = 0; h < 2; ++h)
        __builtin_amdgcn_global_load_lds(AS1(gB + (size_t)h * 128 * K + koff),
                                         AS3((char*)Bs[nxt] + h * 8192 + sdst), 16, 0, 0);
    }
    __builtin_amdgcn_s_barrier();
    asm volatile("s_waitcnt lgkmcnt(0)" ::: "memory");
    __builtin_amdgcn_sched_barrier(0);
    __builtin_amdgcn_s_setprio(1);
#pragma unroll
    for (int mi = 0; mi < 4; ++mi)
#pragma unroll
      for (int ni = 0; ni < 4; ++ni)
        acc[4 + mi][ni] = __builtin_amdgcn_mfma_f32_16x16x32_f16(bf[ni], af2[mi], acc[4 + mi][ni], 0, 0, 0);
    __builtin_amdgcn_s_setprio(0);
    __builtin_amdgcn_sched_barrier(0);
    // no trailing barrier: next iter-top vmcnt(0)+barrier covers WAR/RAW
    cur = nxt;
  }

  // epilogue (R11-verified transposed mapping): row fixed per (mi,l16),
  // 4 consecutive cols per (ni,quad) -> vector stores.
#pragma unroll
  for (int mi = 0; mi < 8; ++mi) {
    const long row = m0 + wm * 128 + mi * 16 + l16;
#pragma unroll
    for (int ni = 0; ni < 4; ++ni) {
      const long col = n0 + wn * 64 + ni * 16 + quad * 4;   // %4 == 0
      const float* bp;
      if (MODE == 3) bp = (col < HDIM) ? (bias + col) : (bias2 + (col - HDIM));
      else           bp = bias + col;
      f32x4 v = acc[mi][ni] + *(const f32x4*)bp;
      if (MODE == 2) {
#pragma unroll
        for (int r = 0; r < 4; ++r) v[r] = v[r] / (1.f + __expf(-v[r]));
      }
      if (MODE == 3) {
        if (col < HDIM) {
          f16x4 o;
#pragma unroll
          for (int r = 0; r < 4; ++r) o[r] = (f16)v[r];
          *(f16x4*)((f16*)Cout + row * HDIM + col) = o;
        } else {
          f16x4 o;
#pragma unroll
          for (int r = 0; r < 4; ++r) o[r] = (f16)(1.f / (1.f + __expf(-v[r])));
          *(f16x4*)((f16*)Cout2 + row * HDIM + (col - HDIM)) = o;
        }
      } else {
        if (RESID) {
          f16x4 rv = *(const f16x4*)(resid + row * N + col);
#pragma unroll
          for (int r = 0; r < 4; ++r) v[r] += (float)rv[r];
        }
        if (OUTF16) {
          f16x4 o;
#pragma unroll
          for (int r = 0; r < 4; ++r) o[r] = (f16)v[r];
          *(f16x4*)((f16*)Cout + row * N + col) = o;
        } else {
          *(f32x4*)((float*)Cout + row * N + col) = v;
        }
      }
    }
  }
}

// -------- scan pass 1: per-chunk local fwd & bwd carries (one read pass) ----
__global__ __launch_bounds__(256) void scan_p1(const f16* __restrict__ u,
                                               const float* __restrict__ sdecay,
                                               float* __restrict__ carry_f,
                                               float* __restrict__ carry_b) {
  int tid = blockIdx.x * 256 + threadIdx.x;
  int h = tid & (HDIM - 1);
  int c = tid >> 10;
  float d = 1.f / (1.f + expf(-sdecay[h]));
  const f16* up = u + (size_t)c * CH * HDIM + h;
  float sf = 0.f, sb = 0.f, p = 1.f;
#pragma unroll
  for (int i = 0; i < CH; i++) {
    float uu = (float)up[i * HDIM];
    sf = d * sf + uu;   // local fwd final
    sb += p * uu;       // local bwd final = sum d^i * u_i
    p *= d;
  }
  carry_f[(size_t)c * HDIM + h] = sf;
  carry_b[(size_t)c * HDIM + h] = sb;
}

// -------- scan pass 2: chunk-level exclusive scans (fwd dir=0, bwd dir=1) --
__global__ __launch_bounds__(256) void scan_p2(const float* __restrict__ sdecay,
                                               const float* __restrict__ carry_f,
                                               const float* __restrict__ carry_b,
                                               float* __restrict__ cin_f,
                                               float* __restrict__ cin_b) {
  int tid = blockIdx.x * 256 + threadIdx.x;  // 2048 threads
  int h = tid & (HDIM - 1);
  int dir = tid >> 10;
  float d = 1.f / (1.f + expf(-sdecay[h]));
  float dT = powf(d, (float)CH);
  float S = 0.f;
  if (dir == 0) {
#pragma unroll 4
    for (int c = 0; c < NC; c++) {
      cin_f[(size_t)c * HDIM + h] = S;
      S = dT * S + carry_f[(size_t)c * HDIM + h];
    }
  } else {
#pragma unroll 4
    for (int c = NC - 1; c >= 0; c--) {
      cin_b[(size_t)c * HDIM + h] = S;
      S = dT * S + carry_b[(size_t)c * HDIM + h];
    }
  }
}

// -------- scan pass 3: re-scan chunk with carries, fuse gate, f16 out ------
__global__ __launch_bounds__(256) void scan_p3(const f16* __restrict__ u,
                                               const f16* __restrict__ gate,
                                               const float* __restrict__ sdecay,
                                               const float* __restrict__ cin_f,
                                               const float* __restrict__ cin_b,
                                               f16* __restrict__ state_out) {
  int tid = blockIdx.x * 256 + threadIdx.x;
  int h = tid & (HDIM - 1);
  int c = tid >> 10;
  float d = 1.f / (1.f + expf(-sdecay[h]));
  const f16* up = u    + (size_t)c * CH * HDIM + h;
  const f16* gp = gate + (size_t)c * CH * HDIM + h;
  f16* op = state_out  + (size_t)c * CH * HDIM + h;
  float ur[CH], sf[CH];
#pragma unroll
  for (int i = 0; i < CH; i++) ur[i] = (float)up[i * HDIM];
  float s = cin_f[(size_t)c * HDIM + h];
#pragma unroll
  for (int i = 0; i < CH; i++) { s = d * s + ur[i]; sf[i] = s; }
  s = cin_b[(size_t)c * HDIM + h];
#pragma unroll
  for (int i = CH - 1; i >= 0; i--) {
    s = d * s + ur[i];
    float g = (float)gp[i * HDIM];
    op[i * HDIM] = (f16)(0.5f * (sf[i] + s) * g);
  }
}

extern "C" void kernel_launch(void* const* d_in, const int* in_sizes, int n_in,
                              void* d_out, int out_size, void* d_ws, size_t ws_size,
                              hipStream_t stream) {
  const float* x      = (const float*)d_in[0];
  const float* ln1_w  = (const float*)d_in[1];
  const float* ln1_b  = (const float*)d_in[2];
  const float* W_in   = (const float*)d_in[3];
  const float* b_in   = (const float*)d_in[4];
  const float* W_gate = (const float*)d_in[5];
  const float* b_gate = (const float*)d_in[6];
  const float* W_out  = (const float*)d_in[7];
  const float* b_out  = (const float*)d_in[8];
  const float* sdecay = (const float*)d_in[9];
  const float* ln2_w  = (const float*)d_in[10];
  const float* ln2_b  = (const float*)d_in[11];
  const float* W_ff1  = (const float*)d_in[12];
  const float* b_ff1  = (const float*)d_in[13];
  const float* W_ff2  = (const float*)d_in[14];
  const float* b_ff2  = (const float*)d_in[15];
  float* out = (float*)d_out;

  char* ws = (char*)d_ws;
  const size_t MB32 = 33554432, MB64 = 67108864;
  f16* hidden = (f16*)(ws);                 // 32MB; reused as state_out
  f16* xh     = (f16*)(ws + MB32);          // 32MB f16 copy of x
  f16* u      = (f16*)(ws + 2 * MB32);      // 32MB; reused as h2
  f16* gate   = (f16*)(ws + 3 * MB32);      // 32MB
  f16* x2h    = (f16*)(ws + 4 * MB32);      // 32MB f16 x2
  f16* ff     = (f16*)(ws + 5 * MB32);      // 64MB
  char* wbase = ws + 5 * MB32 + MB64;
  f16* wt_ug  = (f16*)(wbase);                       // 4MB (2048x1024)
  f16* wt_out = (f16*)(wbase + 4194304);             // 2MB
  f16* wt_ff1 = (f16*)(wbase + 4194304 + 2097152);   // 4MB
  f16* wt_ff2 = (f16*)(wbase + 2 * 4194304 + 2097152); // 4MB
  char* cbase = wbase + 3 * 4194304 + 2097152;
  float* carry_f = (float*)(cbase);
  float* carry_b = (float*)(cbase + 2097152);
  float* cin_f   = (float*)(cbase + 2 * 2097152);
  float* cin_b   = (float*)(cbase + 3 * 2097152);
  f16* state_out = hidden;  // hidden dead after fused u/gate GEMM
  f16* h2        = u;       // u dead after scan_p3

  dim3 tb(32, 8);
  wcvt_t<<<dim3(32, 32), tb, 0, stream>>>(W_in,   wt_ug,                 1024, 1024);
  wcvt_t<<<dim3(32, 32), tb, 0, stream>>>(W_gate, wt_ug + 1024 * 1024,   1024, 1024);
  wcvt_t<<<dim3(32, 32), tb, 0, stream>>>(W_out,  wt_out,                1024, 1024);
  wcvt_t<<<dim3(64, 32), tb, 0, stream>>>(W_ff1,  wt_ff1,                1024, 2048);
  wcvt_t<<<dim3(32, 64), tb, 0, stream>>>(W_ff2,  wt_ff2,                2048, 1024);

  ln_k<<<L_SEQ, 256, 0, stream>>>(x, ln1_w, ln1_b, hidden, xh);

  // fused u + gate: N=2048  (64x8 = 512 tiles of 256x256)
  gemm256<3, 0, 1><<<512, 512, 0, stream>>>(hidden, wt_ug, b_in, b_gate, nullptr,
                                            u, gate, L_SEQ, 2048, 1024);

  scan_p1<<<2048, 256, 0, stream>>>(u, sdecay, carry_f, carry_b);
  scan_p2<<<8, 256, 0, stream>>>(sdecay, carry_f, carry_b, cin_f, cin_b);
  scan_p3<<<2048, 256, 0, stream>>>(u, gate, sdecay, cin_f, cin_b, state_out);

  // x2 = x + state_out @ W_out + b_out  (f16 out)  (64x4 = 256 tiles)
  gemm256<0, 1, 1><<<256, 512, 0, stream>>>(state_out, wt_out, b_out, nullptr, xh,
                                            x2h, nullptr, L_SEQ, 1024, 1024);

  ln_k16<<<L_SEQ, 128, 0, stream>>>(x2h, ln2_w, ln2_b, h2);

  gemm256<2, 0, 1><<<512, 512, 0, stream>>>(h2, wt_ff1, b_ff1, nullptr, nullptr,
                                            ff, nullptr, L_SEQ, 2048, 1024);

  // out = x2 + silu(h2@W_ff1) @ W_ff2 + b_ff2  (fp32 out)  (64x4 = 256 tiles)
  gemm256<0, 1, 0><<<256, 512, 0, stream>>>(ff, wt_ff2, b_ff2, nullptr, x2h,
                                            out, nullptr, L_SEQ, 1024, 2048);
}

// Round 8
// 578.359 us; speedup vs baseline: 1.1221x; 1.0250x over previous
//
#include <hip/hip_runtime.h>
#include <hip/hip_bf16.h>
#include <hip/hip_fp16.h>

#define L_SEQ 16384
#define HDIM  1024
#define CH    32
#define NC    (L_SEQ / CH)   // 512 chunks

typedef _Float16 f16;
typedef _Float16 f16x8 __attribute__((ext_vector_type(8)));
typedef _Float16 f16x4 __attribute__((ext_vector_type(4)));
typedef float    f32x4 __attribute__((ext_vector_type(4)));

#define AS1(p) (const __attribute__((address_space(1))) void*)(p)
#define AS3(p) (__attribute__((address_space(3))) void*)(p)

// -------- weight convert + transpose: out[n*K+k] = (f16) in[k*N+n] --------
__global__ __launch_bounds__(256) void wcvt_t(const float* __restrict__ in,
                                              f16* __restrict__ out, int K, int N) {
  __shared__ float tile[32][33];
  int n0 = blockIdx.x * 32, k0 = blockIdx.y * 32;
  int tx = threadIdx.x, ty = threadIdx.y;  // (32,8)
#pragma unroll
  for (int i = 0; i < 4; i++) {
    int k = k0 + ty + i * 8;
    tile[ty + i * 8][tx] = in[(size_t)k * N + n0 + tx];
  }
  __syncthreads();
#pragma unroll
  for (int i = 0; i < 4; i++) {
    int n = n0 + ty + i * 8;
    out[(size_t)n * K + k0 + tx] = (f16)tile[tx][ty + i * 8];
  }
}

// -------- LayerNorm fp32 in -> f16 out (+ optional f16 copy of input) -----
__global__ __launch_bounds__(256) void ln_k(const float* __restrict__ x,
                                            const float* __restrict__ w,
                                            const float* __restrict__ b,
                                            f16* __restrict__ out,
                                            f16* __restrict__ xcopy) {
  int row = blockIdx.x;
  int t = threadIdx.x;
  const float4* xr = (const float4*)(x + (size_t)row * HDIM);
  float4 v = xr[t];
  float s  = v.x + v.y + v.z + v.w;
  float s2 = v.x * v.x + v.y * v.y + v.z * v.z + v.w * v.w;
#pragma unroll
  for (int off = 32; off > 0; off >>= 1) {
    s  += __shfl_down(s, off);
    s2 += __shfl_down(s2, off);
  }
  __shared__ float red[8];
  int wid = t >> 6, lane = t & 63;
  if (lane == 0) { red[wid] = s; red[4 + wid] = s2; }
  __syncthreads();
  if (t == 0) {
    red[0] = red[0] + red[1] + red[2] + red[3];
    red[4] = red[4] + red[5] + red[6] + red[7];
  }
  __syncthreads();
  float mean = red[0] * (1.0f / HDIM);
  float var  = red[4] * (1.0f / HDIM) - mean * mean;
  float rstd = rsqrtf(var + 1e-5f);
  float4 ww = ((const float4*)w)[t];
  float4 bb = ((const float4*)b)[t];
  f16x4 o;
  o[0] = (f16)((v.x - mean) * rstd * ww.x + bb.x);
  o[1] = (f16)((v.y - mean) * rstd * ww.y + bb.y);
  o[2] = (f16)((v.z - mean) * rstd * ww.z + bb.z);
  o[3] = (f16)((v.w - mean) * rstd * ww.w + bb.w);
  ((f16x4*)(out + (size_t)row * HDIM))[t] = o;
  if (xcopy) {
    f16x4 c;
    c[0] = (f16)v.x; c[1] = (f16)v.y; c[2] = (f16)v.z; c[3] = (f16)v.w;
    ((f16x4*)(xcopy + (size_t)row * HDIM))[t] = c;
  }
}

// -------- LayerNorm f16 in -> f16 out, 128 thr/row, f16x8 loads --------
__global__ __launch_bounds__(128) void ln_k16(const f16* __restrict__ x,
                                              const float* __restrict__ w,
                                              const float* __restrict__ b,
                                              f16* __restrict__ out) {
  int row = blockIdx.x;
  int t = threadIdx.x;  // 0..127
  f16x8 xv = ((const f16x8*)(x + (size_t)row * HDIM))[t];
  float v[8];
  float s = 0.f, s2 = 0.f;
#pragma unroll
  for (int i = 0; i < 8; i++) {
    v[i] = (float)xv[i];
    s += v[i]; s2 += v[i] * v[i];
  }
#pragma unroll
  for (int off = 32; off > 0; off >>= 1) {
    s  += __shfl_down(s, off);
    s2 += __shfl_down(s2, off);
  }
  __shared__ float red[4];
  int wid = t >> 6, lane = t & 63;
  if (lane == 0) { red[wid] = s; red[2 + wid] = s2; }
  __syncthreads();
  float mean = (red[0] + red[1]) * (1.0f / HDIM);
  float var  = (red[2] + red[3]) * (1.0f / HDIM) - mean * mean;
  float rstd = rsqrtf(var + 1e-5f);
  float4 w1 = ((const float4*)w)[2 * t], w2 = ((const float4*)w)[2 * t + 1];
  float4 b1 = ((const float4*)b)[2 * t], b2 = ((const float4*)b)[2 * t + 1];
  float wv[8] = {w1.x, w1.y, w1.z, w1.w, w2.x, w2.y, w2.z, w2.w};
  float bv[8] = {b1.x, b1.y, b1.z, b1.w, b2.x, b2.y, b2.z, b2.w};
  f16x8 o;
#pragma unroll
  for (int i = 0; i < 8; i++) o[i] = (f16)((v[i] - mean) * rstd * wv[i] + bv[i]);
  ((f16x8*)(out + (size_t)row * HDIM))[t] = o;
}

// -------- GEMM: C[M,N] = act(A[M,K] @ BT[N,K]^T + bias) (+f16 resid) --------
// R13 = R12 (verified 592.8us: 256x256, 8 waves, 2 interleaved phases,
// swizzle, setprio, vector epilogue) + PREFETCH DISTANCE 2 / COUNTED VMCNT:
//   3-buffer LDS rotation (3 x 32KB = 96KB, 1 block/CU — m201's proven
//   operating point). During iter t: phase 0 issues A-stage of tile t+2,
//   phase 1 issues B-stage of t+2, into buf[(t+2)%3]. Iter-top wait is
//   vmcnt(4): tile t's 4 per-wave loads (the 4 oldest, issued iter t-2)
//   retired; tile t+1's 4 stay in flight. vmcnt(0) only on the last iter.
//   Barrier after the counted wait makes the per-wave guarantee collective.
//   Issue->wait distance ~2 iters (~900cy) >= HBM latency (T4, m218:
//   counted-vs-drain0 = +38% at this phase structure).
// Race ledger: RAW buf[t%3] <- vmcnt(4)+barrier (per-wave own 4 loads ->
// collective via barrier). WAR buf[(t+2)%3]=buf[(t-1)%3] <- its last reads
// were in iter t-1, all waves passed them before iter t's top barrier;
// stages issued after it.
// MODE: 0=none 2=silu 3=ug-split. XCD-banded 1-D grid swizzle.
template <int MODE, int RESID, int OUTF16>
__global__ __launch_bounds__(512, 2) void gemm256(const f16* __restrict__ A,
                                                  const f16* __restrict__ BT,
                                                  const float* __restrict__ bias,
                                                  const float* __restrict__ bias2,
                                                  const f16* __restrict__ resid,
                                                  void* __restrict__ Cout,
                                                  void* __restrict__ Cout2,
                                                  int M, int N, int K) {
  __shared__ __align__(16) f16 As[3][256 * 32];   // 3 x 16KB
  __shared__ __align__(16) f16 Bs[3][256 * 32];   // 3 x 16KB
  const int tid  = threadIdx.x;
  const int lane = tid & 63;
  const int wid  = tid >> 6;                 // 8 waves
  const int wm = wid >> 2, wn = wid & 3;     // 2 x 4 wave grid
  const int quad = lane >> 4, l16 = lane & 15;
  const int xq = (quad ^ ((l16 >> 1) & 3)) << 4;   // swizzled 16B slot (bytes)

  // XCD-banded swizzle over 256x256 tiles
  const int nbx = N >> 8, nby = M >> 8;
  const int b = blockIdx.x;
  const int xcd = b & 7;
  const int i = b >> 3;
  const int strips = nby >> 3;               // row strips per XCD
  const int rs = i / nbx, cb = i - rs * nbx;
  const long m0 = (long)(xcd * strips + rs) << 8;
  const long n0 = (long)cb << 8;

  // staging: unit = 128 rows x 32 k = 8KB = 512 thr x 16B (1 load each).
  // dest row = tid>>2, phys slot = tid&3; logical source slot pre-swizzled:
  // qs = (tid&3) ^ ((row>>1)&3) = (tid&3) ^ ((tid>>3)&3)   (rule #21)
  const int srow = tid >> 2;
  const int qs = (tid & 3) ^ ((tid >> 3) & 3);
  const f16* gA = A  + (size_t)(m0 + srow) * K + qs * 8;
  const f16* gB = BT + (size_t)(n0 + srow) * K + qs * 8;
  const int sdst = tid * 16;                 // byte offset within an 8KB unit

  f32x4 zero = {0.f, 0.f, 0.f, 0.f};
  f32x4 acc[8][4];
#pragma unroll
  for (int mi = 0; mi < 8; ++mi)
#pragma unroll
    for (int ni = 0; ni < 4; ++ni) acc[mi][ni] = zero;

  // prologue: stage tiles 0 and 1 into buffers 0 and 1 (8 loads per thread)
#pragma unroll
  for (int pt = 0; pt < 2; ++pt) {
    const size_t koff = (size_t)pt * 32;
#pragma unroll
    for (int h = 0; h < 2; ++h) {
      __builtin_amdgcn_global_load_lds(AS1(gA + (size_t)h * 128 * K + koff),
                                       AS3((char*)As[pt] + h * 8192 + sdst), 16, 0, 0);
      __builtin_amdgcn_global_load_lds(AS1(gB + (size_t)h * 128 * K + koff),
                                       AS3((char*)Bs[pt] + h * 8192 + sdst), 16, 0, 0);
    }
  }

  const int nt = K >> 5;
  int cur = 0;                               // t % 3
  for (int t = 0; t < nt; ++t) {
    // counted wait: tile t's 4 (oldest) landed; t+1's 4 stay in flight
    if (t < nt - 1) asm volatile("s_waitcnt vmcnt(4)" ::: "memory");
    else            asm volatile("s_waitcnt vmcnt(0)" ::: "memory");
    __builtin_amdgcn_sched_barrier(0);
    __builtin_amdgcn_s_barrier();
    const f16* Ab = As[cur];
    const f16* Bb = Bs[cur];
    const int stg = (cur + 2 >= 3) ? cur - 1 : cur + 2;   // (t+2)%3

    // ---- phase 0: A-frags mi 0-3 + all B-frags; stage A of t+2 ----
    f16x8 af[4], bf[4];
#pragma unroll
    for (int mi = 0; mi < 4; ++mi) {
      const int row = wm * 128 + mi * 16 + l16;
      af[mi] = *(const f16x8*)((const char*)Ab + row * 64 + xq);
    }
#pragma unroll
    for (int ni = 0; ni < 4; ++ni) {
      const int row = wn * 64 + ni * 16 + l16;
      bf[ni] = *(const f16x8*)((const char*)Bb + row * 64 + xq);
    }
    if (t + 2 < nt) {
      const size_t koff = (size_t)(t + 2) * 32;
#pragma unroll
      for (int h = 0; h < 2; ++h)
        __builtin_amdgcn_global_load_lds(AS1(gA + (size_t)h * 128 * K + koff),
                                         AS3((char*)As[stg] + h * 8192 + sdst), 16, 0, 0);
    }
    __builtin_amdgcn_s_barrier();
    asm volatile("s_waitcnt lgkmcnt(0)" ::: "memory");
    __builtin_amdgcn_sched_barrier(0);
    __builtin_amdgcn_s_setprio(1);
#pragma unroll
    for (int mi = 0; mi < 4; ++mi)
#pragma unroll
      for (int ni = 0; ni < 4; ++ni)
        acc[mi][ni] = __builtin_amdgcn_mfma_f32_16x16x32_f16(bf[ni], af[mi], acc[mi][ni], 0, 0, 0);
    __builtin_amdgcn_s_setprio(0);
    __builtin_amdgcn_sched_barrier(0);
    __builtin_amdgcn_s_barrier();

    // ---- phase 1: A-frags mi 4-7 (B held in regs); stage B of t+2 ----
    f16x8 af2[4];
#pragma unroll
    for (int mi = 0; mi < 4; ++mi) {
      const int row = wm * 128 + (4 + mi) * 16 + l16;
      af2[mi] = *(const f16x8*)((const char*)Ab + row * 64 + xq);
    }
    if (t + 2 < nt) {
      const size_t koff = (size_t)(t + 2) * 32;
#pragma unroll
      for (int h = 0; h < 2; ++h)
        __builtin_amdgcn_global_load_lds(AS1(gB + (size_t)h * 128 * K + koff),
                                         AS3((char*)Bs[stg] + h * 8192 + sdst), 16, 0, 0);
    }
    __builtin_amdgcn_s_barrier();
    asm volatile("s_waitcnt lgkmcnt(0)" ::: "memory");
    __builtin_amdgcn_sched_barrier(0);
    __builtin_amdgcn_s_setprio(1);
#pragma unroll
    for (int mi = 0; mi < 4; ++mi)
#pragma unroll
      for (int ni = 0; ni < 4; ++ni)
        acc[4 + mi][ni] = __builtin_amdgcn_mfma_f32_16x16x32_f16(bf[ni], af2[mi], acc[4 + mi][ni], 0, 0, 0);
    __builtin_amdgcn_s_setprio(0);
    __builtin_amdgcn_sched_barrier(0);
    // no trailing barrier: next iter-top vmcnt+barrier covers WAR/RAW
    cur = (cur == 2) ? 0 : cur + 1;
  }

  // epilogue (R11-verified transposed mapping): row fixed per (mi,l16),
  // 4 consecutive cols per (ni,quad) -> vector stores.
#pragma unroll
  for (int mi = 0; mi < 8; ++mi) {
    const long row = m0 + wm * 128 + mi * 16 + l16;
#pragma unroll
    for (int ni = 0; ni < 4; ++ni) {
      const long col = n0 + wn * 64 + ni * 16 + quad * 4;   // %4 == 0
      const float* bp;
      if (MODE == 3) bp = (col < HDIM) ? (bias + col) : (bias2 + (col - HDIM));
      else           bp = bias + col;
      f32x4 v = acc[mi][ni] + *(const f32x4*)bp;
      if (MODE == 2) {
#pragma unroll
        for (int r = 0; r < 4; ++r) v[r] = v[r] / (1.f + __expf(-v[r]));
      }
      if (MODE == 3) {
        if (col < HDIM) {
          f16x4 o;
#pragma unroll
          for (int r = 0; r < 4; ++r) o[r] = (f16)v[r];
          *(f16x4*)((f16*)Cout + row * HDIM + col) = o;
        } else {
          f16x4 o;
#pragma unroll
          for (int r = 0; r < 4; ++r) o[r] = (f16)(1.f / (1.f + __expf(-v[r])));
          *(f16x4*)((f16*)Cout2 + row * HDIM + (col - HDIM)) = o;
        }
      } else {
        if (RESID) {
          f16x4 rv = *(const f16x4*)(resid + row * N + col);
#pragma unroll
          for (int r = 0; r < 4; ++r) v[r] += (float)rv[r];
        }
        if (OUTF16) {
          f16x4 o;
#pragma unroll
          for (int r = 0; r < 4; ++r) o[r] = (f16)v[r];
          *(f16x4*)((f16*)Cout + row * N + col) = o;
        } else {
          *(f32x4*)((float*)Cout + row * N + col) = v;
        }
      }
    }
  }
}

// -------- scan pass 1: per-chunk local fwd & bwd carries (one read pass) ----
__global__ __launch_bounds__(256) void scan_p1(const f16* __restrict__ u,
                                               const float* __restrict__ sdecay,
                                               float* __restrict__ carry_f,
                                               float* __restrict__ carry_b) {
  int tid = blockIdx.x * 256 + threadIdx.x;
  int h = tid & (HDIM - 1);
  int c = tid >> 10;
  float d = 1.f / (1.f + expf(-sdecay[h]));
  const f16* up = u + (size_t)c * CH * HDIM + h;
  float sf = 0.f, sb = 0.f, p = 1.f;
#pragma unroll
  for (int i = 0; i < CH; i++) {
    float uu = (float)up[i * HDIM];
    sf = d * sf + uu;   // local fwd final
    sb += p * uu;       // local bwd final = sum d^i * u_i
    p *= d;
  }
  carry_f[(size_t)c * HDIM + h] = sf;
  carry_b[(size_t)c * HDIM + h] = sb;
}

// -------- scan pass 2: chunk-level exclusive scans (fwd dir=0, bwd dir=1) --
__global__ __launch_bounds__(256) void scan_p2(const float* __restrict__ sdecay,
                                               const float* __restrict__ carry_f,
                                               const float* __restrict__ carry_b,
                                               float* __restrict__ cin_f,
                                               float* __restrict__ cin_b) {
  int tid = blockIdx.x * 256 + threadIdx.x;  // 2048 threads
  int h = tid & (HDIM - 1);
  int dir = tid >> 10;
  float d = 1.f / (1.f + expf(-sdecay[h]));
  float dT = powf(d, (float)CH);
  float S = 0.f;
  if (dir == 0) {
#pragma unroll 4
    for (int c = 0; c < NC; c++) {
      cin_f[(size_t)c * HDIM + h] = S;
      S = dT * S + carry_f[(size_t)c * HDIM + h];
    }
  } else {
#pragma unroll 4
    for (int c = NC - 1; c >= 0; c--) {
      cin_b[(size_t)c * HDIM + h] = S;
      S = dT * S + carry_b[(size_t)c * HDIM + h];
    }
  }
}

// -------- scan pass 3: re-scan chunk with carries, fuse gate, f16 out ------
__global__ __launch_bounds__(256) void scan_p3(const f16* __restrict__ u,
                                               const f16* __restrict__ gate,
                                               const float* __restrict__ sdecay,
                                               const float* __restrict__ cin_f,
                                               const float* __restrict__ cin_b,
                                               f16* __restrict__ state_out) {
  int tid = blockIdx.x * 256 + threadIdx.x;
  int h = tid & (HDIM - 1);
  int c = tid >> 10;
  float d = 1.f / (1.f + expf(-sdecay[h]));
  const f16* up = u    + (size_t)c * CH * HDIM + h;
  const f16* gp = gate + (size_t)c * CH * HDIM + h;
  f16* op = state_out  + (size_t)c * CH * HDIM + h;
  float ur[CH], sf[CH];
#pragma unroll
  for (int i = 0; i < CH; i++) ur[i] = (float)up[i * HDIM];
  float s = cin_f[(size_t)c * HDIM + h];
#pragma unroll
  for (int i = 0; i < CH; i++) { s = d * s + ur[i]; sf[i] = s; }
  s = cin_b[(size_t)c * HDIM + h];
#pragma unroll
  for (int i = CH - 1; i >= 0; i--) {
    s = d * s + ur[i];
    float g = (float)gp[i * HDIM];
    op[i * HDIM] = (f16)(0.5f * (sf[i] + s) * g);
  }
}

extern "C" void kernel_launch(void* const* d_in, const int* in_sizes, int n_in,
                              void* d_out, int out_size, void* d_ws, size_t ws_size,
                              hipStream_t stream) {
  const float* x      = (const float*)d_in[0];
  const float* ln1_w  = (const float*)d_in[1];
  const float* ln1_b  = (const float*)d_in[2];
  const float* W_in   = (const float*)d_in[3];
  const float* b_in   = (const float*)d_in[4];
  const float* W_gate = (const float*)d_in[5];
  const float* b_gate = (const float*)d_in[6];
  const float* W_out  = (const float*)d_in[7];
  const float* b_out  = (const float*)d_in[8];
  const float* sdecay = (const float*)d_in[9];
  const float* ln2_w  = (const float*)d_in[10];
  const float* ln2_b  = (const float*)d_in[11];
  const float* W_ff1  = (const float*)d_in[12];
  const float* b_ff1  = (const float*)d_in[13];
  const float* W_ff2  = (const float*)d_in[14];
  const float* b_ff2  = (const float*)d_in[15];
  float* out = (float*)d_out;

  char* ws = (char*)d_ws;
  const size_t MB32 = 33554432, MB64 = 67108864;
  f16* hidden = (f16*)(ws);                 // 32MB; reused as state_out
  f16* xh     = (f16*)(ws + MB32);          // 32MB f16 copy of x
  f16* u      = (f16*)(ws + 2 * MB32);      // 32MB; reused as h2
  f16* gate   = (f16*)(ws + 3 * MB32);      // 32MB
  f16* x2h    = (f16*)(ws + 4 * MB32);      // 32MB f16 x2
  f16* ff     = (f16*)(ws + 5 * MB32);      // 64MB
  char* wbase = ws + 5 * MB32 + MB64;
  f16* wt_ug  = (f16*)(wbase);                       // 4MB (2048x1024)
  f16* wt_out = (f16*)(wbase + 4194304);             // 2MB
  f16* wt_ff1 = (f16*)(wbase + 4194304 + 2097152);   // 4MB
  f16* wt_ff2 = (f16*)(wbase + 2 * 4194304 + 2097152); // 4MB
  char* cbase = wbase + 3 * 4194304 + 2097152;
  float* carry_f = (float*)(cbase);
  float* carry_b = (float*)(cbase + 2097152);
  float* cin_f   = (float*)(cbase + 2 * 2097152);
  float* cin_b   = (float*)(cbase + 3 * 2097152);
  f16* state_out = hidden;  // hidden dead after fused u/gate GEMM
  f16* h2        = u;       // u dead after scan_p3

  dim3 tb(32, 8);
  wcvt_t<<<dim3(32, 32), tb, 0, stream>>>(W_in,   wt_ug,                 1024, 1024);
  wcvt_t<<<dim3(32, 32), tb, 0, stream>>>(W_gate, wt_ug + 1024 * 1024,   1024, 1024);
  wcvt_t<<<dim3(32, 32), tb, 0, stream>>>(W_out,  wt_out,                1024, 1024);
  wcvt_t<<<dim3(64, 32), tb, 0, stream>>>(W_ff1,  wt_ff1,                1024, 2048);
  wcvt_t<<<dim3(32, 64), tb, 0, stream>>>(W_ff2,  wt_ff2,                2048, 1024);

  ln_k<<<L_SEQ, 256, 0, stream>>>(x, ln1_w, ln1_b, hidden, xh);

  // fused u + gate: N=2048  (64x8 = 512 tiles of 256x256)
  gemm256<3, 0, 1><<<512, 512, 0, stream>>>(hidden, wt_ug, b_in, b_gate, nullptr,
                                            u, gate, L_SEQ, 2048, 1024);

  scan_p1<<<2048, 256, 0, stream>>>(u, sdecay, carry_f, carry_b);
  scan_p2<<<8, 256, 0, stream>>>(sdecay, carry_f, carry_b, cin_f, cin_b);
  scan_p3<<<2048, 256, 0, stream>>>(u, gate, sdecay, cin_f, cin_b, state_out);

  // x2 = x + state_out @ W_out + b_out  (f16 out)  (64x4 = 256 tiles)
  gemm256<0, 1, 1><<<256, 512, 0, stream>>>(state_out, wt_out, b_out, nullptr, xh,
                                            x2h, nullptr, L_SEQ, 1024, 1024);

  ln_k16<<<L_SEQ, 128, 0, stream>>>(x2h, ln2_w, ln2_b, h2);

  gemm256<2, 0, 1><<<512, 512, 0, stream>>>(h2, wt_ff1, b_ff1, nullptr, nullptr,
                                            ff, nullptr, L_SEQ, 2048, 1024);

  // out = x2 + silu(h2@W_ff1) @ W_ff2 + b_ff2  (fp32 out)  (64x4 = 256 tiles)
  gemm256<0, 1, 0><<<256, 512, 0, stream>>>(ff, wt_ff2, b_ff2, nullptr, x2h,
                                            out, nullptr, L_SEQ, 1024, 2048);
}